// Round 16
// baseline (18.593 us; speedup 1.0000x reference)
//
#include <hip/hip_runtime.h>

#define B_ 4
#define J_ 8160               // 68*120 cells per batch
#define NQ_ 2040              // quads per batch
#define HF 544
#define WF 960
#define TS 32
#define TYN 17
#define NPX 15                // tile-PAIRS per row (64px wide)
#define NPPB (NPX*TYN)        // 255 pairs/batch; grid = 1020 blocks = ~4/CU
#define R2COEF 23.0259f       // 2*ln(1e5): exact per-cell cut (d^2 <= R2COEF*var)

typedef _Float16 half8 __attribute__((ext_vector_type(8)));
typedef float floatx16 __attribute__((ext_vector_type(16)));

// SINGLE plain dispatch; R15 structure (pair tiles, quad-scan, single-segment
// compaction) with two overlap-slack fixes:
//   - scan unrolled x2: all 8 cache-line loads (2 quads x {2 mean, var, conf})
//     issued at the top of the body -> 8 independent L2 streams in flight;
//   - epilogue in ONE barrier round: red[4][32][64] aliases the full 32KB
//     queue arena; accL/accR written side by side; each thread then reduces
//     and stores 8 coalesced pixels. (R15 had 4 barriers + 2 LDS passes.)
// Queue discipline unchanged: cap 512, guard after each quad-group keeps the
// worst-case write index at 255+255 = 510 < 512.
// Drain: 8 ey (shared) + 8 exL + 8 exR, TWO v_mfma_f32_32x32x16_f16 (layout
// validated R3-R15: cell -> same k-slot (half,i) in A and B; C/D
// row=(r&3)+8*(r>>2)+4*half).
__global__ __launch_bounds__(256, 4) void pif_pair(const float2* __restrict__ mean,
                                                   const float*  __restrict__ var,
                                                   const float*  __restrict__ conf,
                                                   float* __restrict__ out) {
    __shared__ float4 qbuf[4][512];    // per-wave queues (32KB); red[] alias later
    int wid  = threadIdx.x >> 6;
    int lane = threadIdx.x & 63;
    int pair = blockIdx.x;             // 0..254
    int b    = blockIdx.y;

    int pty = pair / NPX;
    int ptx = pair - pty * NPX;

    const float4* mb4 = (const float4*)(mean + (size_t)b * J_);  // [2k],[2k+1]
    const float4* vb4 = (const float4*)(var  + (size_t)b * J_);  // [k]: 4 vars
    const float4* cb4 = (const float4*)(conf + (size_t)b * J_);  // [k]: 4 confs

    float4* q = qbuf[wid];
    int qn = 0;

    float x0 = (float)(ptx * 64), y0 = (float)(pty * TS);
    float x1 = x0 + 63.f,         y1 = y0 + 31.f;   // union box of the 2 tiles
    int   lx = lane & 31, half = lane >> 5;
    float xfL = x0 + (float)lx;
    float xfR = x0 + 32.f + (float)lx;
    float yf  = y0 + (float)lx;
    const unsigned long long below = (1ull << lane) - 1ull;

    floatx16 accL = {}, accR = {};

    auto drain16 = [&](int base) {     // consumes q[base..base+15], LDS-only
        half8 af, bfl, bfr;
        #pragma unroll
        for (int i = 0; i < 8; ++i) {
            float4 e = q[base + 8 * half + i];   // uniform per half-wave: broadcast
            float dy  = yf  - e.y;
            float dxl = xfL - e.x;
            float dxr = xfR - e.x;
            af[i]  = (_Float16)__expf(-dy * dy * e.z);
            float c = e.w;
            bfl[i] = (_Float16)(c * __expf(-dxl * dxl * e.z));  // w=0 -> inert
            bfr[i] = (_Float16)(c * __expf(-dxr * dxr * e.z));
        }
        accL = __builtin_amdgcn_mfma_f32_32x32x16_f16(af, bfl, accL, 0, 0, 0);
        accR = __builtin_amdgcn_mfma_f32_32x32x16_f16(af, bfr, accR, 0, 0, 0);
    };

    // clamped-point squared distance to the union box
    auto pdist2 = [&](float mx, float my) {
        float ddx = mx - fminf(fmaxf(mx, x0), x1);
        float ddy = my - fminf(fmaxf(my, y0), y1);
        return ddx * ddx + ddy * ddy;
    };

    // test+compact one quad (4 cells) given its preloaded data
    auto compact4 = [&](bool valid, float4 m01, float4 m23, float4 vv, float4 cc) {
        float dd0 = pdist2(m01.x, m01.y);
        float dd1 = pdist2(m01.z, m01.w);
        float dd2 = pdist2(m23.x, m23.y);
        float dd3 = pdist2(m23.z, m23.w);
        bool p0 = valid & (cc.x > 0.1f) & (dd0 <= R2COEF * vv.x);
        bool p1 = valid & (cc.y > 0.1f) & (dd1 <= R2COEF * vv.y);
        bool p2 = valid & (cc.z > 0.1f) & (dd2 <= R2COEF * vv.z);
        bool p3 = valid & (cc.w > 0.1f) & (dd3 <= R2COEF * vv.w);

        unsigned long long m0 = __ballot(p0);
        unsigned long long m1 = __ballot(p1);
        unsigned long long m2 = __ballot(p2);
        unsigned long long m3 = __ballot(p3);
        int c0 = __popcll(m0), c1 = __popcll(m1), c2 = __popcll(m2);
        if (p0) q[qn + __popcll(m0 & below)] =
            make_float4(m01.x, m01.y, __builtin_amdgcn_rcpf(2.0f * vv.x), cc.x);
        if (p1) q[qn + c0 + __popcll(m1 & below)] =
            make_float4(m01.z, m01.w, __builtin_amdgcn_rcpf(2.0f * vv.y), cc.y);
        if (p2) q[qn + c0 + c1 + __popcll(m2 & below)] =
            make_float4(m23.x, m23.y, __builtin_amdgcn_rcpf(2.0f * vv.z), cc.z);
        if (p3) q[qn + c0 + c1 + c2 + __popcll(m3 & below)] =
            make_float4(m23.z, m23.w, __builtin_amdgcn_rcpf(2.0f * vv.w), cc.w);
        qn += c0 + c1 + c2 + __popcll(m3);

        if (__builtin_expect(qn >= 256, 0)) {  // keeps qn <= 255 post-group
            while (qn >= 16) { qn -= 16; drain16(qn); }
        }
    };

    const int kbase = wid * 512;               // this wave's 512 quads
    #pragma unroll
    for (int s = 0; s < 4; ++s) {
        int  ka = kbase + s * 128 + lane;      // quad A
        int  kb = ka + 64;                     // quad B
        bool va = ka < NQ_;
        bool vb = kb < NQ_;
        int  kca = va ? ka : 0;
        int  kcb = vb ? kb : 0;

        // all 8 loads issued together: 8 independent L2 streams per lane
        float4 a01 = mb4[2 * kca];
        float4 a23 = mb4[2 * kca + 1];
        float4 b01 = mb4[2 * kcb];
        float4 b23 = mb4[2 * kcb + 1];
        float4 av  = vb4[kca];
        float4 bv  = vb4[kcb];
        float4 ac  = cb4[kca];
        float4 bc  = cb4[kcb];

        compact4(va, a01, a23, av, ac);
        compact4(vb, b01, b23, bv, bc);
    }

    while (qn >= 16) { qn -= 16; drain16(qn); }
    if (qn > 0) {                              // pad tail to a full chunk
        if (lane >= qn && lane < 16)
            q[lane] = make_float4(0.f, 0.f, 0.f, 0.f);   // cf=0: inert
        drain16(0);                            // wave-local LDS: no barrier needed
    }

    // ---- Epilogue, ONE barrier round: each wave's red slice == its own
    // (dead) queue region, so no pre-write barrier is needed.
    float (*red)[32][64] = (float (*)[32][64])qbuf;      // [4][32][64] = 32 KB
    #pragma unroll
    for (int r = 0; r < 16; ++r) {
        int row = (r & 3) + 8 * (r >> 2) + 4 * half;
        red[wid][row][lx]      = accL[r];      // 2-way bank alias: free
        red[wid][row][32 + lx] = accR[r];
    }
    __syncthreads();

    int th = threadIdx.x;
    #pragma unroll
    for (int kk = 0; kk < 8; ++kk) {
        int p   = th + 256 * kk;               // 0..2047 = 32 rows x 64 cols
        int row = p >> 6, col = p & 63;
        float s = red[0][row][col] + red[1][row][col]
                + red[2][row][col] + red[3][row][col];
        out[((size_t)(b * HF + pty * TS + row)) * WF + (ptx * 64 + col)] = s;
    }
}

extern "C" void kernel_launch(void* const* d_in, const int* in_sizes, int n_in,
                              void* d_out, int out_size, void* d_ws, size_t ws_size,
                              hipStream_t stream) {
    const float2* mean = (const float2*)d_in[0];
    const float*  var  = (const float*)d_in[1];
    const float*  conf = (const float*)d_in[2];
    float* out = (float*)d_out;
    (void)d_ws; (void)ws_size;

    pif_pair<<<dim3(NPPB, B_), 256, 0, stream>>>(mean, var, conf, out);
}